// Round 2
// baseline (494.852 us; speedup 1.0000x reference)
//
#include <hip/hip_runtime.h>
#include <hip/hip_fp16.h>

#define BB 32
#define NI 2048
#define NK 64
#define ND 32
#define NL 16
#define KD (NK*ND)     // 2048
#define IT 8           // i's per block
#define NT (NI/IT)     // 256 blocks
#define EPSF 1e-7f

typedef _Float16 h2 __attribute__((ext_vector_type(2)));

union U4H8 { uint4 u; h2 h[4]; };
union UH2  { unsigned u; h2 h; };

static __device__ __forceinline__ float dot2f(h2 a, h2 b, float c) {
#if __has_builtin(__builtin_amdgcn_fdot2)
  return __builtin_amdgcn_fdot2(a, b, c, false);
#else
  return c + (float)a[0] * (float)b[0] + (float)a[1] * (float)b[1];
#endif
}

static __device__ __forceinline__ h2 pack2(float x, float y) {
  h2 r; r[0] = (_Float16)x; r[1] = (_Float16)y; return r;
}

// Stage x[b][i0..i0+7][:] into LDS as f16 pairs.
static __device__ __forceinline__ void stage_x(const float* __restrict__ x,
                                               h2 (*xs)[BB][8], int i0, int t) {
  for (int q = t; q < IT * BB * 8; q += 512) {
    const int l2 = q & 7, b = (q >> 3) & 31, ii = q >> 8;
    const float2 f = *(const float2*)&x[((size_t)b * NI + (i0 + ii)) * NL + 2 * l2];
    xs[ii][b][l2] = pack2(f.x, f.y);
  }
}

// K1: convert W->f16 (swizzled uint4 layout Whs[i][q][tid]) + fused round-0 partial
// (c uniform = 1/64): part[b][blk][cell] f16 = (1/64) * sum_{i in tile} u.
__global__ __launch_bounds__(512, 2) void k_conv(const float* __restrict__ x,
                                                 const float* __restrict__ W,
                                                 uint4* __restrict__ Whs,
                                                 __half* __restrict__ part) {
  const int blk = blockIdx.x, t = threadIdx.x;
  const int i0 = blk * IT;
  __shared__ h2 xs[IT][BB][8];
  stage_x(x, xs, i0, t);
  __syncthreads();

  float sacc[4][BB];
  #pragma unroll
  for (int c = 0; c < 4; ++c)
    #pragma unroll
    for (int b = 0; b < BB; ++b) sacc[c][b] = 0.f;

  for (int ii = 0; ii < IT; ++ii) {
    const float* Wp = W + ((size_t)(i0 + ii) * KD + 4 * t) * NL;
    h2 wh[4][8];
    #pragma unroll
    for (int c = 0; c < 4; ++c) {
      const float4 f0 = *(const float4*)(Wp + c * NL + 0);
      const float4 f1 = *(const float4*)(Wp + c * NL + 4);
      const float4 f2 = *(const float4*)(Wp + c * NL + 8);
      const float4 f3 = *(const float4*)(Wp + c * NL + 12);
      wh[c][0] = pack2(f0.x, f0.y); wh[c][1] = pack2(f0.z, f0.w);
      wh[c][2] = pack2(f1.x, f1.y); wh[c][3] = pack2(f1.z, f1.w);
      wh[c][4] = pack2(f2.x, f2.y); wh[c][5] = pack2(f2.z, f2.w);
      wh[c][6] = pack2(f3.x, f3.y); wh[c][7] = pack2(f3.z, f3.w);
      U4H8 a, b2;
      a.h[0] = wh[c][0]; a.h[1] = wh[c][1]; a.h[2] = wh[c][2]; a.h[3] = wh[c][3];
      b2.h[0] = wh[c][4]; b2.h[1] = wh[c][5]; b2.h[2] = wh[c][6]; b2.h[3] = wh[c][7];
      Whs[((size_t)(i0 + ii) * 8 + 2 * c) * 512 + t]     = a.u;
      Whs[((size_t)(i0 + ii) * 8 + 2 * c + 1) * 512 + t] = b2.u;
    }
    #pragma unroll
    for (int b = 0; b < BB; ++b) {
      U4H8 ux0, ux1;
      ux0.u = *(const uint4*)&xs[ii][b][0];
      ux1.u = *(const uint4*)&xs[ii][b][4];
      float u0 = 0.f, u1 = 0.f, u2 = 0.f, u3 = 0.f;
      #pragma unroll
      for (int j = 0; j < 4; ++j) {
        u0 = dot2f(wh[0][j], ux0.h[j], u0); u0 = dot2f(wh[0][4 + j], ux1.h[j], u0);
        u1 = dot2f(wh[1][j], ux0.h[j], u1); u1 = dot2f(wh[1][4 + j], ux1.h[j], u1);
        u2 = dot2f(wh[2][j], ux0.h[j], u2); u2 = dot2f(wh[2][4 + j], ux1.h[j], u2);
        u3 = dot2f(wh[3][j], ux0.h[j], u3); u3 = dot2f(wh[3][4 + j], ux1.h[j], u3);
      }
      sacc[0][b] += u0; sacc[1][b] += u1; sacc[2][b] += u2; sacc[3][b] += u3;
    }
  }
  #pragma unroll
  for (int b = 0; b < BB; ++b) {
    UH2 p0, p1;
    p0.h = pack2(sacc[0][b] * (1.f / 64.f), sacc[1][b] * (1.f / 64.f));
    p1.h = pack2(sacc[2][b] * (1.f / 64.f), sacc[3][b] * (1.f / 64.f));
    *(uint2*)&part[((size_t)b * NT + blk) * KD + 4 * t] = make_uint2(p0.u, p1.u);
  }
}

// Routing round: recompute u from Whs, logits = u . vin, softmax over k (3-phase LDS),
// accumulate s partials. Used for round 1 (vin = v0) and round 2 (vin = v0+v1).
__global__ __launch_bounds__(512, 2) void k_route(const float* __restrict__ x,
                                                  const uint4* __restrict__ Whs,
                                                  const float* __restrict__ vin,
                                                  __half* __restrict__ part) {
  const int blk = blockIdx.x, t = threadIdx.x;
  const int i0 = blk * IT;
  const int k = t >> 3;
  const int lane = t & 63, wv = t >> 6;
  __shared__ h2 xs[IT][BB][8];       // 8 KB
  __shared__ h2 uS[BB][KD / 2];      // 128 KB: u[b][cell] f16
  __shared__ float smc[BB][NK];      // 8 KB: logits, then c
  stage_x(x, xs, i0, t);
  __syncthreads();

  float sacc[4][BB];
  #pragma unroll
  for (int c = 0; c < 4; ++c)
    #pragma unroll
    for (int b = 0; b < BB; ++b) sacc[c][b] = 0.f;

  h2 wh[4][8];
  {
    #pragma unroll
    for (int q = 0; q < 8; ++q) {
      U4H8 r; r.u = Whs[((size_t)i0 * 8 + q) * 512 + t];
      wh[q >> 1][(q & 1) * 4 + 0] = r.h[0]; wh[q >> 1][(q & 1) * 4 + 1] = r.h[1];
      wh[q >> 1][(q & 1) * 4 + 2] = r.h[2]; wh[q >> 1][(q & 1) * 4 + 3] = r.h[3];
    }
  }

  for (int ii = 0; ii < IT; ++ii) {
    // ---- phase A: u (f16->LDS) + agreement logits ----
    for (int b = 0; b < BB; ++b) {
      U4H8 ux0, ux1;
      ux0.u = *(const uint4*)&xs[ii][b][0];
      ux1.u = *(const uint4*)&xs[ii][b][4];
      float u0 = 0.f, u1 = 0.f, u2 = 0.f, u3 = 0.f;
      #pragma unroll
      for (int j = 0; j < 4; ++j) {
        u0 = dot2f(wh[0][j], ux0.h[j], u0); u0 = dot2f(wh[0][4 + j], ux1.h[j], u0);
        u1 = dot2f(wh[1][j], ux0.h[j], u1); u1 = dot2f(wh[1][4 + j], ux1.h[j], u1);
        u2 = dot2f(wh[2][j], ux0.h[j], u2); u2 = dot2f(wh[2][4 + j], ux1.h[j], u2);
        u3 = dot2f(wh[3][j], ux0.h[j], u3); u3 = dot2f(wh[3][4 + j], ux1.h[j], u3);
      }
      const float4 vv = *(const float4*)&vin[(size_t)b * KD + 4 * t];
      float ag = u0 * vv.x + u1 * vv.y + u2 * vv.z + u3 * vv.w;
      ag += __shfl_xor(ag, 1); ag += __shfl_xor(ag, 2); ag += __shfl_xor(ag, 4);
      UH2 a0, a1; a0.h = pack2(u0, u1); a1.h = pack2(u2, u3);
      *(uint2*)&uS[b][2 * t] = make_uint2(a0.u, a1.u);
      if ((t & 7) == 0) smc[b][k] = ag;
    }
    // prefetch next Wh tile (stays in flight across barriers)
    uint4 pf[8];
    if (ii + 1 < IT) {
      #pragma unroll
      for (int q = 0; q < 8; ++q)
        pf[q] = Whs[((size_t)(i0 + ii + 1) * 8 + q) * 512 + t];
    }
    __syncthreads();
    // ---- phase B: softmax over k=64, one wave owns 4 b rows ----
    #pragma unroll
    for (int j = 0; j < 4; ++j) {
      const int b = wv * 4 + j;
      const float lg = smc[b][lane];
      float m = lg;
      m = fmaxf(m, __shfl_xor(m, 1));  m = fmaxf(m, __shfl_xor(m, 2));
      m = fmaxf(m, __shfl_xor(m, 4));  m = fmaxf(m, __shfl_xor(m, 8));
      m = fmaxf(m, __shfl_xor(m, 16)); m = fmaxf(m, __shfl_xor(m, 32));
      const float e = __expf(lg - m);
      float s = e;
      s += __shfl_xor(s, 1);  s += __shfl_xor(s, 2);  s += __shfl_xor(s, 4);
      s += __shfl_xor(s, 8);  s += __shfl_xor(s, 16); s += __shfl_xor(s, 32);
      smc[b][lane] = e / s;
    }
    __syncthreads();
    // ---- phase C: sacc += c * u ----
    #pragma unroll
    for (int b = 0; b < BB; ++b) {
      const float c_ = smc[b][k];
      const uint2 up = *(const uint2*)&uS[b][2 * t];
      UH2 w0, w1; w0.u = up.x; w1.u = up.y;
      sacc[0][b] += c_ * (float)w0.h[0]; sacc[1][b] += c_ * (float)w0.h[1];
      sacc[2][b] += c_ * (float)w1.h[0]; sacc[3][b] += c_ * (float)w1.h[1];
    }
    __syncthreads();
    if (ii + 1 < IT) {
      #pragma unroll
      for (int q = 0; q < 8; ++q) {
        U4H8 r; r.u = pf[q];
        wh[q >> 1][(q & 1) * 4 + 0] = r.h[0]; wh[q >> 1][(q & 1) * 4 + 1] = r.h[1];
        wh[q >> 1][(q & 1) * 4 + 2] = r.h[2]; wh[q >> 1][(q & 1) * 4 + 3] = r.h[3];
      }
    }
  }
  #pragma unroll
  for (int b = 0; b < BB; ++b) {
    UH2 p0, p1;
    p0.h = pack2(sacc[0][b], sacc[1][b]);
    p1.h = pack2(sacc[2][b], sacc[3][b]);
    *(uint2*)&part[((size_t)b * NT + blk) * KD + 4 * t] = make_uint2(p0.u, p1.u);
  }
}

// Reduce partials over NT chunks, squash over d=32; optionally add vprev
// (round-1 output becomes v0+v1 for the linear-agreement trick).
__global__ __launch_bounds__(256) void k_reduce(const __half* __restrict__ part,
                                                const float* __restrict__ vprev,
                                                float* __restrict__ vout) {
  const int g = blockIdx.x, b = blockIdx.y, t = threadIdx.x;
  const int p = g * 256 + t;           // h2-pair index, cells 2p, 2p+1
  const h2* pp = (const h2*)part;
  const size_t base = (size_t)b * NT * (KD / 2) + p;
  float sa0 = 0.f, sa1 = 0.f, sb0 = 0.f, sb1 = 0.f;
  for (int ch = 0; ch < NT; ch += 2) {
    const h2 va = pp[base + (size_t)ch * (KD / 2)];
    const h2 vb = pp[base + (size_t)(ch + 1) * (KD / 2)];
    sa0 += (float)va[0]; sa1 += (float)va[1];
    sb0 += (float)vb[0]; sb1 += (float)vb[1];
  }
  const float s0 = sa0 + sb0, s1 = sa1 + sb1;
  float sq = s0 * s0 + s1 * s1;
  sq += __shfl_xor(sq, 1); sq += __shfl_xor(sq, 2);
  sq += __shfl_xor(sq, 4); sq += __shfl_xor(sq, 8);
  sq += EPSF;
  const float sc = sqrtf(sq) / (1.f + sq);
  float r0 = s0 * sc, r1 = s1 * sc;
  if (vprev != nullptr) {
    r0 += vprev[(size_t)b * KD + 2 * p];
    r1 += vprev[(size_t)b * KD + 2 * p + 1];
  }
  *(float2*)&vout[(size_t)b * KD + 2 * p] = make_float2(r0, r1);
}

extern "C" void kernel_launch(void* const* d_in, const int* in_sizes, int n_in,
                              void* d_out, int out_size, void* d_ws, size_t ws_size,
                              hipStream_t stream) {
  const float* x = (const float*)d_in[0];   // [32, 2048, 16]
  const float* W = (const float*)d_in[1];   // [2048, 64, 32, 16]
  float* out = (float*)d_out;               // [32, 64, 32]
  char* ws = (char*)d_ws;
  uint4*  Whs  = (uint4*)ws;                               // 134217728 B
  __half* part = (__half*)(ws + 134217728ull);             // 33554432 B
  float*  vA   = (float*)(ws + 134217728ull + 33554432ull);// 262144 B
  float*  vB   = vA + (size_t)BB * KD;                     // 262144 B

  k_conv<<<NT, 512, 0, stream>>>(x, W, Whs, part);
  k_reduce<<<dim3(4, BB), 256, 0, stream>>>(part, nullptr, vA);   // vA = v0
  k_route<<<NT, 512, 0, stream>>>(x, Whs, vA, part);              // logits u.v0
  k_reduce<<<dim3(4, BB), 256, 0, stream>>>(part, vA, vB);        // vB = v0 + v1
  k_route<<<NT, 512, 0, stream>>>(x, Whs, vB, part);              // logits u.(v0+v1)
  k_reduce<<<dim3(4, BB), 256, 0, stream>>>(part, nullptr, out);  // out = v2
}

// Round 3
// 340.932 us; speedup vs baseline: 1.4515x; 1.4515x over previous
//
#include <hip/hip_runtime.h>
#include <hip/hip_fp16.h>

#define BB 32
#define NI 2048
#define NK 64
#define KD 2048       // caps_n * caps_dim
#define NL 16
#define IT 8          // i's per conv block
#define NTC (NI/IT)   // 256 conv chunks
#define RCH 32        // i's per route block
#define NRC (NI/RCH)  // 64 route chunks
#define EPSF 1e-7f

typedef _Float16 h2 __attribute__((ext_vector_type(2)));
union UH2  { unsigned u; h2 h; };
union U4H8 { uint4 u4; h2 h[4]; };

static __device__ __forceinline__ float dot2f(h2 a, h2 b, float c) {
#if __has_builtin(__builtin_amdgcn_fdot2)
  return __builtin_amdgcn_fdot2(a, b, c, false);
#else
  return c + (float)a[0] * (float)b[0] + (float)a[1] * (float)b[1];
#endif
}

static __device__ __forceinline__ h2 pack2(float x, float y) {
  h2 r; r[0] = (_Float16)x; r[1] = (_Float16)y; return r;
}

// K1: u_hat[b][i][cell] f16 = sum_l W[i][cell][l] * x[b][i][l], fused with the
// round-0 partial (softmax of zero logits -> c = 1/64 uniform):
// part[b][blk][cell] f16 = (1/64) * sum_{i in tile} u.
// 1024 threads, thread t owns cells 2t, 2t+1. grid = NTC.
__global__ __launch_bounds__(1024) void k_conv(const float* __restrict__ x,
                                               const float* __restrict__ W,
                                               __half* __restrict__ uhat,
                                               __half* __restrict__ part) {
  const int blk = blockIdx.x, t = threadIdx.x;
  const int i0 = blk * IT;
  __shared__ h2 xs[IT][BB][8];
  for (int q = t; q < IT * BB * 8; q += 1024) {
    const int l2 = q & 7, b = (q >> 3) & 31, ii = q >> 8;
    const float2 f = *(const float2*)&x[((size_t)b * NI + (i0 + ii)) * NL + 2 * l2];
    xs[ii][b][l2] = pack2(f.x, f.y);
  }
  __syncthreads();

  float sacc0[BB], sacc1[BB];
  #pragma unroll
  for (int b = 0; b < BB; ++b) { sacc0[b] = 0.f; sacc1[b] = 0.f; }

  for (int ii = 0; ii < IT; ++ii) {
    const float* Wp = W + ((size_t)(i0 + ii) * KD + 2 * t) * NL;
    h2 w0[8], w1[8];
    #pragma unroll
    for (int q = 0; q < 4; ++q) {
      const float4 f = *(const float4*)(Wp + 4 * q);
      w0[2 * q] = pack2(f.x, f.y); w0[2 * q + 1] = pack2(f.z, f.w);
    }
    #pragma unroll
    for (int q = 0; q < 4; ++q) {
      const float4 f = *(const float4*)(Wp + NL + 4 * q);
      w1[2 * q] = pack2(f.x, f.y); w1[2 * q + 1] = pack2(f.z, f.w);
    }
    #pragma unroll
    for (int b = 0; b < BB; ++b) {
      U4H8 ux0, ux1;
      ux0.u4 = *(const uint4*)&xs[ii][b][0];
      ux1.u4 = *(const uint4*)&xs[ii][b][4];
      float u0 = 0.f, u1 = 0.f;
      #pragma unroll
      for (int j = 0; j < 4; ++j) {
        u0 = dot2f(w0[j], ux0.h[j], u0); u0 = dot2f(w0[4 + j], ux1.h[j], u0);
        u1 = dot2f(w1[j], ux0.h[j], u1); u1 = dot2f(w1[4 + j], ux1.h[j], u1);
      }
      UH2 p; p.h = pack2(u0, u1);
      *(unsigned*)&uhat[((size_t)b * NI + (i0 + ii)) * KD + 2 * t] = p.u;
      sacc0[b] += u0; sacc1[b] += u1;
    }
  }
  #pragma unroll
  for (int b = 0; b < BB; ++b) {
    UH2 p; p.h = pack2(sacc0[b] * (1.f / 64.f), sacc1[b] * (1.f / 64.f));
    *(unsigned*)&part[((size_t)b * NTC + blk) * KD + 2 * t] = p.u;
  }
}

// Routing round: read u_hat, agreement logits = u . vin, softmax over k=64
// (no max-subtract; logits bounded), weighted partial accumulate.
// grid (NRC, BB), 256 threads; thread owns cells 8t..8t+7 (k = t>>2).
__global__ __launch_bounds__(256) void k_route(const __half* __restrict__ uhat,
                                               const float* __restrict__ vin,
                                               __half* __restrict__ part) {
  const int ch = blockIdx.x, b = blockIdx.y, t = threadIdx.x;
  const int lane = t & 63, wv = t >> 6;
  __shared__ float ssum[2][4];
  float vr[8];
  *(float4*)&vr[0] = *(const float4*)&vin[(size_t)b * KD + 8 * t];
  *(float4*)&vr[4] = *(const float4*)&vin[(size_t)b * KD + 8 * t + 4];
  float sacc[8];
  #pragma unroll
  for (int j = 0; j < 8; ++j) sacc[j] = 0.f;

  const __half* up = uhat + ((size_t)b * NI + (size_t)ch * RCH) * KD + 8 * t;
  U4H8 cur; cur.u4 = *(const uint4*)up;
  for (int il = 0; il < RCH; ++il) {
    U4H8 nxt;
    if (il + 1 < RCH) nxt.u4 = *(const uint4*)(up + (size_t)(il + 1) * KD);
    float uf[8];
    #pragma unroll
    for (int j = 0; j < 4; ++j) {
      uf[2 * j] = (float)cur.h[j][0];
      uf[2 * j + 1] = (float)cur.h[j][1];
    }
    float ag = 0.f;
    #pragma unroll
    for (int j = 0; j < 8; ++j) ag += uf[j] * vr[j];
    ag += __shfl_xor(ag, 1);
    ag += __shfl_xor(ag, 2);            // full dot over d=32 (4 threads per k)
    const float e = __expf(ag);
    float s = e;
    s += __shfl_xor(s, 4);  s += __shfl_xor(s, 8);
    s += __shfl_xor(s, 16); s += __shfl_xor(s, 32);   // sum over 16 k's in wave
    if (lane == 0) ssum[il & 1][wv] = s;
    __syncthreads();
    const float stot = ssum[il & 1][0] + ssum[il & 1][1] +
                       ssum[il & 1][2] + ssum[il & 1][3];
    const float c = e / stot;
    #pragma unroll
    for (int j = 0; j < 8; ++j) sacc[j] += c * uf[j];
    cur = nxt;
  }
  U4H8 o;
  o.h[0] = pack2(sacc[0], sacc[1]); o.h[1] = pack2(sacc[2], sacc[3]);
  o.h[2] = pack2(sacc[4], sacc[5]); o.h[3] = pack2(sacc[6], sacc[7]);
  *(uint4*)&part[((size_t)b * NRC + ch) * KD + 8 * t] = o.u4;
}

// Reduce partials over nch chunks, squash over d=32; optional vprev add
// (round-1 output becomes v0+v1 for the linear-agreement trick).
__global__ __launch_bounds__(256) void k_reduce(const __half* __restrict__ part,
                                                int nch,
                                                const float* __restrict__ vprev,
                                                float* __restrict__ vout) {
  const int g = blockIdx.x, b = blockIdx.y, t = threadIdx.x;
  const int p = g * 256 + t;            // h2-pair index: cells 2p, 2p+1
  const h2* pp = (const h2*)part;
  const size_t base = (size_t)b * nch * (KD / 2) + p;
  float s0 = 0.f, s1 = 0.f;
  for (int ch = 0; ch < nch; ++ch) {
    const h2 v = pp[base + (size_t)ch * (KD / 2)];
    s0 += (float)v[0]; s1 += (float)v[1];
  }
  float sq = s0 * s0 + s1 * s1;
  sq += __shfl_xor(sq, 1); sq += __shfl_xor(sq, 2);
  sq += __shfl_xor(sq, 4); sq += __shfl_xor(sq, 8);
  sq += EPSF;
  const float sc = sqrtf(sq) / (1.f + sq);
  float r0 = s0 * sc, r1 = s1 * sc;
  if (vprev != nullptr) {
    r0 += vprev[(size_t)b * KD + 2 * p];
    r1 += vprev[(size_t)b * KD + 2 * p + 1];
  }
  *(float2*)&vout[(size_t)b * KD + 2 * p] = make_float2(r0, r1);
}

extern "C" void kernel_launch(void* const* d_in, const int* in_sizes, int n_in,
                              void* d_out, int out_size, void* d_ws, size_t ws_size,
                              hipStream_t stream) {
  const float* x = (const float*)d_in[0];   // [32, 2048, 16]
  const float* W = (const float*)d_in[1];   // [2048, 64, 32, 16]
  float* out = (float*)d_out;               // [32, 64, 32]
  char* ws = (char*)d_ws;
  __half* uhat = (__half*)ws;                                   // 268435456 B
  __half* part = (__half*)(ws + 268435456ull);                  // 33554432 B
  float*  vA   = (float*)(ws + 268435456ull + 33554432ull);     // 262144 B
  float*  vB   = vA + (size_t)BB * KD;                          // 262144 B

  k_conv<<<NTC, 1024, 0, stream>>>(x, W, uhat, part);
  k_reduce<<<dim3(4, BB), 256, 0, stream>>>(part, NTC, nullptr, vA);  // vA = v0
  k_route<<<dim3(NRC, BB), 256, 0, stream>>>(uhat, vA, part);         // logits u.v0
  k_reduce<<<dim3(4, BB), 256, 0, stream>>>(part, NRC, vA, vB);       // vB = v0+v1
  k_route<<<dim3(NRC, BB), 256, 0, stream>>>(uhat, vB, part);         // logits u.(v0+v1)
  k_reduce<<<dim3(4, BB), 256, 0, stream>>>(part, NRC, nullptr, out); // out = v2
}